// Round 3
// baseline (220.806 us; speedup 1.0000x reference)
//
#include <hip/hip_runtime.h>
#include <stdint.h>

// AM-softmax loss, fused on MI355X (gfx950) — round 11.
//
// vs round 10 (214 us; gemm 122.5 us, MfmaUtil 26, FETCH 40.7 MB, HBM 4.7%):
//  * Round 10 proved the gemm is NOT bandwidth-bound (7.4x FETCH cut, zero
//    time change). The r9/r10 regression vs r8's 91 us is per-block breg
//    setup (36 strided loads + ~500 VALU f2bf) paid by 5.45 lockstep
//    generations. Non-gemm time is ~85 us fixed harness overhead.
//  * PERSISTENT blocks: grid=768 (3/CU), each block loops virtual items j.
//    The band DMA chain bridges j-boundaries (band 7 prefetches next j's
//    band 0) -> no generation-restart stall; resident blocks desync and
//    cover each other's setup/epilogue on the MFMA pipe.
//  * BANDS 4->8 (block = 512 rows, RYB=4): breg setup amortized 2x; only
//    2.75 j's per slot. Rowsums via 2 KB double-buffered rs scratch with
//    lagged per-band stores (LDS 51.2 KB -> still 3 blocks/CU).
//  * v_cvt_pk_bf16_f32 (RNE, bit-identical to f2bf): 72 instrs replace
//    ~500 VALU in the breg build.
//  * XCD map kept: slots 4k..4k+3 of an XCD = the 4 ry of one cx panel.

constexpr int N  = 2048;
constexpr int D  = 192;               // K
constexpr int C  = 100000;
constexpr int KT = D / 32;            // 6 k-tiles of 32
constexpr int TILE = 512;             // elems per 16x32 fragment tile
constexpr int RT16 = C / 16;          // 6250 real 16-col tiles
constexpr int TPG = 12;               // 16-col tiles per block (4 waves x 3)
constexpr int CX = 523;               // col groups: 523*12 = 6276 tiles
constexpr int NT16 = CX * TPG;        // 6276 tiles = 100416 cols
constexpr float PHANTOM = (float)(NT16 * 16 - C);   // 416 exact ones
constexpr int BANDS = 8;              // 64-row bands per virtual block
constexpr int RYB = N / (64 * BANDS); // 4 row groups
constexpr int BUF = 4 * KT * TILE;    // 12288 ushort = 24 KB per band buffer
constexpr int NXB = N / 4;            // 512 prep_x blocks
constexpr int CXG = 66;               // cx groups of 8 -> covers 528 >= 523
constexpr int JMAX = CXG * RYB;       // 264 virtual items per XCD
constexpr int SLOTS = 96;             // physical block slots per XCD
constexpr int GRID = SLOTS * 8;       // 768 = 3 blocks/CU

#define S_SCALE 30.0f
#define MARGIN  0.2f
#define S_LOG2E 43.2808512266689f     // 30 * log2(e)

using short8 = __attribute__((ext_vector_type(8))) short;   // 8 bf16 (4 VGPRs)
using f32x4  = __attribute__((ext_vector_type(4))) float;   // MFMA C/D

typedef __attribute__((address_space(1))) const void GV;
typedef __attribute__((address_space(3))) void LV;

__device__ inline unsigned short f2bf(float f) {  // fp32 -> bf16 RNE
  unsigned int u = __float_as_uint(f);
  u += 0x7fffu + ((u >> 16) & 1u);
  return (unsigned short)(u >> 16);
}

__device__ inline unsigned int cvtpk(float lo, float hi) {  // bf16(hi)<<16 | bf16(lo), RNE
  unsigned int r;
  asm("v_cvt_pk_bf16_f32 %0, %1, %2" : "=v"(r) : "v"(lo), "v"(hi));
  return r;
}

// packed fragment index (ushort units) for element (row r, k):
// tile (r>>4, k>>5), lane = (r&15) + ((k>>3)&3)*16, elem k&7.
__device__ inline int pack_idx(int r, int k) {
  return ((r >> 4) * KT + (k >> 5)) * TILE + (((k >> 3) & 3) * 16 + (r & 15)) * 8 + (k & 7);
}

// Sum across each 16-lane DPP row; result valid in all 16 lanes.
__device__ inline float row_sum16(float v) {
  int x;
  x = __float_as_int(v);
  v += __int_as_float(__builtin_amdgcn_update_dpp(0, x, 0x128, 0xF, 0xF, true)); // row_ror:8
  x = __float_as_int(v);
  v += __int_as_float(__builtin_amdgcn_update_dpp(0, x, 0x124, 0xF, 0xF, true)); // row_ror:4
  x = __float_as_int(v);
  v += __int_as_float(__builtin_amdgcn_update_dpp(0, x, 0x04E, 0xF, 0xF, true)); // quad_perm xor2
  x = __float_as_int(v);
  v += __int_as_float(__builtin_amdgcn_update_dpp(0, x, 0x0B1, 0xF, 0xF, true)); // quad_perm xor1
  return v;
}

// ---------------- prep: x-normalize + pack (+ zero out[0]) ----------------
__global__ __launch_bounds__(256) void prep_x(
    const float* __restrict__ x, unsigned short* __restrict__ xnb,
    float* __restrict__ out) {
  const int bid  = blockIdx.x;
  const int lane = threadIdx.x & 63;
  if (bid == 0 && threadIdx.x == 0) out[0] = 0.0f;   // for finalize atomics

  const int row = bid * 4 + (threadIdx.x >> 6);
  const float* xr = x + (size_t)row * D;
  float v0 = xr[lane], v1 = xr[lane + 64], v2 = xr[lane + 128];
  float ss = v0 * v0 + v1 * v1 + v2 * v2;
#pragma unroll
  for (int off = 32; off > 0; off >>= 1) ss += __shfl_xor(ss, off, 64);
  const float inv = rsqrtf(ss) * S_LOG2E;
  xnb[pack_idx(row, lane)]       = f2bf(v0 * inv);
  xnb[pack_idx(row, lane + 64)]  = f2bf(v1 * inv);
  xnb[pack_idx(row, lane + 128)] = f2bf(v2 * inv);
}

// issue one 24 KB band DMA (1536 x 16 B chunks across 256 threads)
#define DMA_BAND(DSTBYTES, SLABIDX)                                          \
  {                                                                          \
    const char* _src = (const char*)(xnb + (size_t)(SLABIDX) * BUF);         \
    char* _dst = (char*)As + (size_t)(DSTBYTES);                             \
    _Pragma("unroll")                                                        \
    for (int _i = 0; _i < 6; ++_i) {                                         \
      const int _c = tid + _i * 256;                                         \
      __builtin_amdgcn_global_load_lds((GV*)(_src + (size_t)_c * 16),        \
                                       (LV*)(_dst + (size_t)_c * 16), 16, 0, 0); \
    }                                                                        \
  }

// ---------------- main fused GEMM + exp-rowsum (persistent) ---------------
// grid 768 (3/CU). xcd = bid&7, slot = bid>>3 in [0,96). Virtual items
// j = slot + k*96 < 264: ry = j&3, cx = (j>>2)*8 + xcd. Slots 4k..4k+3 of
// an XCD are the 4 ry of one cx panel (L2 reuse). Per j: breg fp32->bf16
// once, then 8 bands of 64 rows, A double-buffered, DMA chained across j.
__global__ __launch_bounds__(256, 3) void gemm_lse(
    const unsigned short* __restrict__ xnb,  // packed [128 row-tiles][KT][512]
    const float* __restrict__ W,             // [C][D] fp32, row-major
    float* __restrict__ partial) {           // [CX][N]
  __shared__ alignas(16) unsigned short As[2 * BUF];   // 48 KB (double buffer)
  __shared__ alignas(16) float rs[2][4][64];           // 2 KB (double buffer)

  const int tid = threadIdx.x;
  const int bid = blockIdx.x;
  const int xcd = bid & 7, slot = bid >> 3;
  const int lane = tid & 63, wave = tid >> 6;
  const int m = lane & 15, quad = lane >> 4;

  // prologue: DMA band 0 of first j (slot < 96 -> always a real cx)
  DMA_BAND(0, (slot & 3) * BANDS);

  for (int j = slot; j < JMAX; j += SLOTS) {
    const int ry = j & 3;
    const int cx = (j >> 2) * 8 + xcd;
    if (cx >= CX) break;                    // phantom j only occurs last
    const int jn = j + SLOTS;
    const bool next_ok = (jn < JMAX) && (((jn >> 2) * 8 + xcd) < CX);
    const int ryn = jn & 3;

    // ---- B fragments: fp32 W -> bf16 regs via v_cvt_pk (once per j) ----
    short8 breg[3][KT];
#pragma unroll
    for (int tc = 0; tc < 3; ++tc) {
      const int t16 = cx * TPG + wave * 3 + tc;
      if (t16 < RT16) {
        const float* src = W + (size_t)(t16 * 16 + m) * D + quad * 8;
#pragma unroll
        for (int ks = 0; ks < KT; ++ks) {
          const float4* s4 = (const float4*)(src + ks * 32);
          float4 f0 = s4[0], f1 = s4[1];
          union { uint4 u; short8 s; } cv;
          cv.u.x = cvtpk(f0.x, f0.y);
          cv.u.y = cvtpk(f0.z, f0.w);
          cv.u.z = cvtpk(f1.x, f1.y);
          cv.u.w = cvtpk(f1.z, f1.w);
          breg[tc][ks] = cv.s;
        }
      } else {
        const short8 z = {0, 0, 0, 0, 0, 0, 0, 0};
#pragma unroll
        for (int ks = 0; ks < KT; ++ks) breg[tc][ks] = z;
      }
    }

    const f32x4 zero4 = {0.0f, 0.0f, 0.0f, 0.0f};

    for (int b = 0; b < BANDS; ++b) {
      __syncthreads();   // band b's DMA drained (issued one band-compute ago)

      // prefetch into buf (b+1)&1: next band, or next j's band 0
      if (b + 1 < BANDS) {
        DMA_BAND(((b + 1) & 1) * (BUF * 2), ry * BANDS + b + 1);
      } else if (next_ok) {
        DMA_BAND(0, ryn * BANDS);
      }

      // lagged store of band b-1's rowsums (written before this barrier)
      if (b >= 1 && tid < 64) {
        const int pb = (b - 1) & 1;
        const float s = rs[pb][0][tid] + rs[pb][1][tid] +
                        rs[pb][2][tid] + rs[pb][3][tid];
        partial[(size_t)cx * N + ry * (BANDS * 64) + (b - 1) * 64 + tid] = s;
      }

      const unsigned short* Ab = &As[(b & 1) * BUF];

      f32x4 acc[4][3];
#pragma unroll
      for (int a = 0; a < 4; ++a)
#pragma unroll
        for (int c = 0; c < 3; ++c) acc[a][c] = zero4;

#pragma unroll
      for (int ks = 0; ks < KT; ++ks) {
        short8 af[4];
#pragma unroll
        for (int tr = 0; tr < 4; ++tr)
          af[tr] = *(const short8*)(&Ab[(tr * KT + ks) * TILE + lane * 8]);
#pragma unroll
        for (int tr = 0; tr < 4; ++tr)
#pragma unroll
          for (int tc = 0; tc < 3; ++tc)
            acc[tr][tc] = __builtin_amdgcn_mfma_f32_16x16x32_bf16(
                af[tr], breg[tc][ks], acc[tr][tc], 0, 0, 0);
      }

      // ---- epilogue: exp2 (arg pre-scaled; phantom cols give exactly 1) --
#pragma unroll
      for (int tr = 0; tr < 4; ++tr) {
        float rv0 = 0.f, rv1 = 0.f, rv2 = 0.f, rv3 = 0.f;
#pragma unroll
        for (int tc = 0; tc < 3; ++tc) {
          rv0 += __builtin_amdgcn_exp2f(acc[tr][tc][0]);
          rv1 += __builtin_amdgcn_exp2f(acc[tr][tc][1]);
          rv2 += __builtin_amdgcn_exp2f(acc[tr][tc][2]);
          rv3 += __builtin_amdgcn_exp2f(acc[tr][tc][3]);
        }
        rv0 = row_sum16(rv0);
        rv1 = row_sum16(rv1);
        rv2 = row_sum16(rv2);
        rv3 = row_sum16(rv3);
        if (m == 0) {
          float4 v = make_float4(rv0, rv1, rv2, rv3);
          *(float4*)(&rs[b & 1][wave][tr * 16 + quad * 4]) = v;
        }
      }
    }

    __syncthreads();  // band 7's rs writes visible
    if (tid < 64) {   // tail: store band 7 ((BANDS-1)&1 == 1)
      const float s = rs[1][0][tid] + rs[1][1][tid] + rs[1][2][tid] + rs[1][3][tid];
      partial[(size_t)cx * N + ry * (BANDS * 64) + (BANDS - 1) * 64 + tid] = s;
    }
  }
}

// ---------------- finalize: per-row loss + in-kernel mean reduce ----------
// One wave per row (4 rows/block): gather 523 partials + fp32 target logit in
// one shuffle reduction; block-sum -> one atomicAdd into out[0] (pre-zeroed).
__global__ __launch_bounds__(256) void finalize_rows(
    const float* __restrict__ x, const float* __restrict__ W,
    const int* __restrict__ label, const float* __restrict__ partial,
    float* __restrict__ out) {
  const int row  = blockIdx.x * 4 + (threadIdx.x >> 6);
  const int lane = threadIdx.x & 63;
  const float* xr = x + (size_t)row * D;
  float v0 = xr[lane], v1 = xr[lane + 64], v2 = xr[lane + 128];
  float ss = v0 * v0 + v1 * v1 + v2 * v2;
  const int lab = label[row];
  const float* wr = W + (size_t)lab * D;
  float d = v0 * wr[lane] + v1 * wr[lane + 64] + v2 * wr[lane + 128];
  float p = 0.0f;
  for (int s = lane; s < CX; s += 64) p += partial[(size_t)s * N + row];
#pragma unroll
  for (int off = 32; off > 0; off >>= 1) {
    ss += __shfl_xor(ss, off, 64);
    d  += __shfl_xor(d,  off, 64);
    p  += __shfl_xor(p,  off, 64);
  }
  __shared__ float part[4];
  if (lane == 0) {
    const float tgt   = d * rsqrtf(ss);
    const float numer = S_SCALE * (tgt - MARGIN);
    // remove phantom-ones, swap label column's exp for margin-adjusted exp
    const float se = p - PHANTOM - __expf(S_SCALE * tgt) + __expf(numer);
    part[threadIdx.x >> 6] = numer - logf(se);
  }
  __syncthreads();
  if (threadIdx.x == 0) {
    const float blocksum = part[0] + part[1] + part[2] + part[3];
    atomicAdd(out, -blocksum * (1.0f / (float)N));
  }
}

// ---------------- host ----------------------------------------------------
extern "C" void kernel_launch(void* const* d_in, const int* in_sizes, int n_in,
                              void* d_out, int out_size, void* d_ws, size_t ws_size,
                              hipStream_t stream) {
  const float* x     = (const float*)d_in[0];
  const float* W     = (const float*)d_in[1];
  const int*   label = (const int*)d_in[2];
  float*       out   = (float*)d_out;

  char* ws = (char*)d_ws;
  size_t off = 0;
  unsigned short* xnb = (unsigned short*)(ws + off); off += (size_t)N * D * 2;  // 768 KB
  float* partial = (float*)(ws + off); off += (size_t)CX * N * 4;               // 4.3 MB

  prep_x<<<NXB, 256, 0, stream>>>(x, xnb, out);

  gemm_lse<<<GRID, 256, 0, stream>>>(xnb, W, partial);

  finalize_rows<<<N / 4, 256, 0, stream>>>(x, W, label, partial, out);
}

// Round 6
// 203.872 us; speedup vs baseline: 1.0831x; 1.0831x over previous
//
#include <hip/hip_runtime.h>
#include <stdint.h>

// AM-softmax loss, fused on MI355X (gfx950) — round 14.
//
// vs rounds 12/13 (failed grid-sync-in-one-kernel experiments — abandoned):
// Re-audit of r7-r11 budgets: launch gaps are ~0 (r7->r8: 5->3 launches
// saved only 2 us). The real residual is finalize_rows ~= 88 us: its
// partial[s*N+row] gather reads 4 B per 8 KB stride -> 1.07M line-fetches
// (68 MB), latency-bound. Fix by NEVER materializing [CX][N] partials:
//  * gemm blocks atomicAdd their 256 per-row exp-sums into rowsum[N]
//    (523 fp32 atomics/address spread over ~90 us -> mild contention;
//    order nondeterminism ~1e-6 relative, threshold slack 0.37).
//  * prep_all (r8's proven fused prep restored, cvtpk W-pack) additionally
//    computes the per-row target logit (coalesced W[label] gather + second
//    shuffle reduce) -> aux[row]; zeroes rowsum + out[0].
//  * finalize_tiny: 8 blocks, one thread per row: loss from rowsum/aux,
//    block-reduce, one atomicAdd. ~2 us (was ~88).
//  * gemm = r8's packed-Wb breg structure (91 us proven) + r10's XCD remap
//    (7.4x FETCH cut proven): grid 528*8, xcd=bid&7 -> 8 ry-blocks of one
//    cx panel land on one XCD's L2.

constexpr int N  = 2048;
constexpr int D  = 192;               // K
constexpr int C  = 100000;
constexpr int KT = D / 32;            // 6 k-tiles of 32
constexpr int TILE = 512;             // elems per 16x32 fragment tile
constexpr int RT16 = C / 16;          // 6250 real 16-col tiles
constexpr int TPG = 12;               // 16-col tiles per block (4 waves x 3)
constexpr int CX = 523;               // col groups: 523*12 = 6276 tiles
constexpr int NT16 = CX * TPG;        // 6276 tiles = 100416 cols
constexpr float PHANTOM = (float)(NT16 * 16 - C);   // 416 exact ones
constexpr int BANDS = 4;              // 64-row bands per block
constexpr int RYB = N / (64 * BANDS); // 8 row groups
constexpr int BUF = 4 * KT * TILE;    // 12288 ushort = 24 KB per band buffer
constexpr int NXB = N / 4;            // 512 prep_x blocks
constexpr int CXP = 528;              // cx padded to multiple of 8 (XCD remap)

#define S_SCALE 30.0f
#define MARGIN  0.2f
#define S_LOG2E 43.2808512266689f     // 30 * log2(e)

using short8 = __attribute__((ext_vector_type(8))) short;   // 8 bf16 (4 VGPRs)
using f32x4  = __attribute__((ext_vector_type(4))) float;   // MFMA C/D

typedef __attribute__((address_space(1))) const void GV;
typedef __attribute__((address_space(3))) void LV;

__device__ inline unsigned short f2bf(float f) {  // fp32 -> bf16 RNE
  unsigned int u = __float_as_uint(f);
  u += 0x7fffu + ((u >> 16) & 1u);
  return (unsigned short)(u >> 16);
}

__device__ inline unsigned int cvtpk(float lo, float hi) {  // RNE pack, = f2bf
  unsigned int r;
  asm("v_cvt_pk_bf16_f32 %0, %1, %2" : "=v"(r) : "v"(lo), "v"(hi));
  return r;
}

// packed fragment index (ushort units) for element (row r, k):
// tile (r>>4, k>>5), lane = (r&15) + ((k>>3)&3)*16, elem k&7.
__device__ inline int pack_idx(int r, int k) {
  return ((r >> 4) * KT + (k >> 5)) * TILE + (((k >> 3) & 3) * 16 + (r & 15)) * 8 + (k & 7);
}

// Sum across each 16-lane DPP row; result valid in all 16 lanes.
__device__ inline float row_sum16(float v) {
  int x;
  x = __float_as_int(v);
  v += __int_as_float(__builtin_amdgcn_update_dpp(0, x, 0x128, 0xF, 0xF, true)); // row_ror:8
  x = __float_as_int(v);
  v += __int_as_float(__builtin_amdgcn_update_dpp(0, x, 0x124, 0xF, 0xF, true)); // row_ror:4
  x = __float_as_int(v);
  v += __int_as_float(__builtin_amdgcn_update_dpp(0, x, 0x04E, 0xF, 0xF, true)); // quad_perm xor2
  x = __float_as_int(v);
  v += __int_as_float(__builtin_amdgcn_update_dpp(0, x, 0x0B1, 0xF, 0xF, true)); // quad_perm xor1
  return v;
}

// ---------------- fused prep: x-normalize+pack + target logit + W pack ----
__global__ __launch_bounds__(256) void prep_all(
    const float* __restrict__ x, const float* __restrict__ W,
    const int* __restrict__ label,
    unsigned short* __restrict__ xnb, unsigned short* __restrict__ Wb,
    float* __restrict__ aux, float* __restrict__ rowsum,
    float* __restrict__ out) {
  const int bid  = blockIdx.x;
  const int lane = threadIdx.x & 63;
  if (bid == 0 && threadIdx.x == 0) out[0] = 0.0f;   // for finalize atomics

  if (bid < NXB) {
    // ---- one wave per x row: normalize + pack + target logit ----
    const int row = bid * 4 + (threadIdx.x >> 6);
    const float* xr = x + (size_t)row * D;
    float v0 = xr[lane], v1 = xr[lane + 64], v2 = xr[lane + 128];
    float ss = v0 * v0 + v1 * v1 + v2 * v2;
    const int lab = label[row];
    const float* wr = W + (size_t)lab * D;
    float d = v0 * wr[lane] + v1 * wr[lane + 64] + v2 * wr[lane + 128];
#pragma unroll
    for (int off = 32; off > 0; off >>= 1) {
      ss += __shfl_xor(ss, off, 64);
      d  += __shfl_xor(d,  off, 64);
    }
    const float rinv = rsqrtf(ss);
    const float inv = rinv * S_LOG2E;
    xnb[pack_idx(row, lane)]       = f2bf(v0 * inv);
    xnb[pack_idx(row, lane + 64)]  = f2bf(v1 * inv);
    xnb[pack_idx(row, lane + 128)] = f2bf(v2 * inv);
    if (lane == 0) {
      aux[row]    = d * rinv;   // target logit (unscaled)
      rowsum[row] = 0.0f;       // accumulator for gemm atomics
    }
  } else {
    // ---- one wave per 16-col W tile; tiles >= RT16 exactly zero ----
    const int t16 = (bid - NXB) * 4 + (threadIdx.x >> 6);
    const int m = lane & 15, q = lane >> 4;
    unsigned short* dst = Wb + (size_t)t16 * KT * TILE + lane * 8;
    if (t16 < RT16) {
      const float* src = W + (size_t)(t16 * 16 + m) * D + q * 8;
#pragma unroll
      for (int ks = 0; ks < KT; ++ks) {
        const float4* s4 = (const float4*)(src + ks * 32);
        float4 f0 = s4[0], f1 = s4[1];
        union { uint4 u; short8 s; } cv;
        cv.u.x = cvtpk(f0.x, f0.y);
        cv.u.y = cvtpk(f0.z, f0.w);
        cv.u.z = cvtpk(f1.x, f1.y);
        cv.u.w = cvtpk(f1.z, f1.w);
        *(short8*)(dst + (size_t)ks * TILE) = cv.s;
      }
    } else {
      const short8 z = {0, 0, 0, 0, 0, 0, 0, 0};
#pragma unroll
      for (int ks = 0; ks < KT; ++ks) *(short8*)(dst + (size_t)ks * TILE) = z;
    }
  }
}

// ---------------- main fused GEMM + exp-rowsum ----------------------------
// Grid CXP*RYB (4224). XCD-aware map (r10, proven): xcd=bid&7, j=bid>>3,
// ry=j&7, cx=(j>>3)*8+xcd -> the 8 ry-blocks of one cx are consecutive in
// per-XCD dispatch order (same L2; Wb panel fetched once). Block = 4 waves;
// wave owns 48 cols (breg from packed Wb: 18 coalesced 1 KB wave-loads).
// 4 bands of 64 rows, A double-buffered, DMA prefetch one band ahead.
// Epilogue: per-row exp-sums atomicAdd'ed into rowsum[N] (no [CX][N]
// partial buffer -> kills finalize's 88 us strided gather).
__global__ __launch_bounds__(256, 3) void gemm_lse(
    const unsigned short* __restrict__ xnb,  // packed [128 row-tiles][KT][512]
    const unsigned short* __restrict__ Wb,   // packed [NT16][KT][512]
    float* __restrict__ rowsum) {            // [N] atomic accumulator
  __shared__ alignas(16) unsigned short As[2 * BUF];   // 48 KB (double buffer)
  __shared__ alignas(16) float rs_lds[4][256];         // 4 KB

  const int tid = threadIdx.x;
  const int bid = blockIdx.x;
  const int xcd = bid & 7, j = bid >> 3;
  const int ry = j & 7;
  const int cx = (j >> 3) * 8 + xcd;
  if (cx >= CX) return;                     // 40 phantom blocks (pad to 528)

  // ---- issue DMA for band 0 into buf 0 (24 KB, contiguous packed) ----
  {
    const unsigned short* slab = xnb + (size_t)(ry * BANDS) * BUF;
#pragma unroll
    for (int i = 0; i < 6; ++i) {            // 1536 x 16 B
      const int chunk = tid + i * 256;
      __builtin_amdgcn_global_load_lds(
          (GV*)((const char*)slab + (size_t)chunk * 16),
          (LV*)((char*)As + (size_t)chunk * 16), 16, 0, 0);
    }
  }

  const int lane = tid & 63, wave = tid >> 6;
  const int m = lane & 15, quad = lane >> 4;

  // ---- B fragments from packed Wb (18 coalesced 1 KB wave-loads) ----
  short8 breg[3][KT];
#pragma unroll
  for (int tc = 0; tc < 3; ++tc)
#pragma unroll
    for (int ks = 0; ks < KT; ++ks)
      breg[tc][ks] = *(const short8*)(
          Wb + (size_t)((cx * TPG + wave * 3 + tc) * KT + ks) * TILE + lane * 8);

  const f32x4 zero4 = {0.0f, 0.0f, 0.0f, 0.0f};

  for (int b = 0; b < BANDS; ++b) {
    __syncthreads();   // drains vmcnt: band b's DMA (issued a full band ago)

    // prefetch band b+1 into the other buffer BEFORE compute of band b
    if (b + 1 < BANDS) {
      const unsigned short* slab = xnb + (size_t)(ry * BANDS + b + 1) * BUF;
      char* dst = (char*)&As[((b + 1) & 1) * BUF];
#pragma unroll
      for (int i = 0; i < 6; ++i) {
        const int chunk = tid + i * 256;
        __builtin_amdgcn_global_load_lds(
            (GV*)((const char*)slab + (size_t)chunk * 16),
            (LV*)(dst + (size_t)chunk * 16), 16, 0, 0);
      }
    }

    const unsigned short* Ab = &As[(b & 1) * BUF];

    f32x4 acc[4][3];
#pragma unroll
    for (int a = 0; a < 4; ++a)
#pragma unroll
      for (int c = 0; c < 3; ++c) acc[a][c] = zero4;

#pragma unroll
    for (int ks = 0; ks < KT; ++ks) {
      short8 af[4];
#pragma unroll
      for (int tr = 0; tr < 4; ++tr)
        af[tr] = *(const short8*)(&Ab[(tr * KT + ks) * TILE + lane * 8]);
#pragma unroll
      for (int tr = 0; tr < 4; ++tr)
#pragma unroll
        for (int tc = 0; tc < 3; ++tc)
          acc[tr][tc] = __builtin_amdgcn_mfma_f32_16x16x32_bf16(
              af[tr], breg[tc][ks], acc[tr][tc], 0, 0, 0);
    }

    // ---- epilogue: exp2 (arg pre-scaled; phantom cols give exactly 1) ----
#pragma unroll
    for (int tr = 0; tr < 4; ++tr) {
      float rv0 = 0.f, rv1 = 0.f, rv2 = 0.f, rv3 = 0.f;
#pragma unroll
      for (int tc = 0; tc < 3; ++tc) {
        rv0 += __builtin_amdgcn_exp2f(acc[tr][tc][0]);
        rv1 += __builtin_amdgcn_exp2f(acc[tr][tc][1]);
        rv2 += __builtin_amdgcn_exp2f(acc[tr][tc][2]);
        rv3 += __builtin_amdgcn_exp2f(acc[tr][tc][3]);
      }
      rv0 = row_sum16(rv0);
      rv1 = row_sum16(rv1);
      rv2 = row_sum16(rv2);
      rv3 = row_sum16(rv3);
      if (m == 0) {
        float4 v = make_float4(rv0, rv1, rv2, rv3);
        *(float4*)(&rs_lds[wave][b * 64 + tr * 16 + quad * 4]) = v;
      }
    }
  }

  __syncthreads();  // all waves' rowsums in LDS
  const float s = rs_lds[0][tid] + rs_lds[1][tid] + rs_lds[2][tid] + rs_lds[3][tid];
  atomicAdd(&rowsum[ry * 256 + tid], s);    // 523 adds/address, spread in time
}

// ---------------- finalize: per-row loss + in-kernel mean reduce ----------
// 8 blocks x 256 threads, one thread per row. Reads are fully coalesced.
__global__ __launch_bounds__(256) void finalize_tiny(
    const float* __restrict__ aux, const float* __restrict__ rowsum,
    float* __restrict__ out) {
  const int row  = blockIdx.x * 256 + threadIdx.x;
  const int lane = threadIdx.x & 63, wave = threadIdx.x >> 6;
  const float tgt   = aux[row];
  const float numer = S_SCALE * (tgt - MARGIN);
  // remove phantom-ones, swap label column's exp for margin-adjusted exp
  const float se = rowsum[row] - PHANTOM - __expf(S_SCALE * tgt) + __expf(numer);
  float L = numer - logf(se);
#pragma unroll
  for (int off = 32; off > 0; off >>= 1) L += __shfl_xor(L, off, 64);
  __shared__ float part[4];
  if (lane == 0) part[wave] = L;
  __syncthreads();
  if (threadIdx.x == 0) {
    const float blocksum = part[0] + part[1] + part[2] + part[3];
    atomicAdd(out, -blocksum * (1.0f / (float)N));
  }
}

// ---------------- host ----------------------------------------------------
extern "C" void kernel_launch(void* const* d_in, const int* in_sizes, int n_in,
                              void* d_out, int out_size, void* d_ws, size_t ws_size,
                              hipStream_t stream) {
  const float* x     = (const float*)d_in[0];
  const float* W     = (const float*)d_in[1];
  const int*   label = (const int*)d_in[2];
  float*       out   = (float*)d_out;

  char* ws = (char*)d_ws;
  size_t off = 0;
  unsigned short* xnb = (unsigned short*)(ws + off); off += (size_t)N * D * 2;            // 768 KB
  unsigned short* Wb  = (unsigned short*)(ws + off); off += (size_t)NT16 * KT * TILE * 2; // 38.6 MB
  float* aux    = (float*)(ws + off); off += (size_t)N * 4;                                // 8 KB
  float* rowsum = (float*)(ws + off); off += (size_t)N * 4;                                // 8 KB

  prep_all<<<NXB + NT16 / 4, 256, 0, stream>>>(x, W, label, xnb, Wb, aux, rowsum, out);

  gemm_lse<<<CXP * RYB, 256, 0, stream>>>(xnb, Wb, rowsum);

  finalize_tiny<<<N / 256, 256, 0, stream>>>(aux, rowsum, out);
}